// Round 1
// baseline (5654.770 us; speedup 1.0000x reference)
//
#include <hip/hip_runtime.h>
#include <hip/hip_bf16.h>

namespace {
constexpr int B  = 64;
constexpr int T  = 8;
constexpr int N  = 1000;
constexpr int U  = 64;
constexpr int FK = 195;          // F*K = 65*3
constexpr int R  = B * N;        // 64000 rows
constexpr int CSR_CAP = 65536;
}

// ---------------- CSR build (deterministic, no atomics) ----------------

__global__ __launch_bounds__(256) void k_count(const float* __restrict__ S,
                                               int* __restrict__ rowptr) {
  int lane = threadIdx.x & 63;
  int m = blockIdx.x * 4 + (threadIdx.x >> 6);   // 250 blocks * 4 rows = 1000
  int c = 0;
  for (int n = lane; n < N; n += 64) c += (S[m * N + n] != 0.f) ? 1 : 0;
  for (int off = 32; off; off >>= 1) c += __shfl_down(c, off, 64);
  if (lane == 0) rowptr[m + 1] = c;
}

__global__ __launch_bounds__(1024) void k_scan(int* __restrict__ rowptr) {
  __shared__ int sm[1024];
  int t = threadIdx.x;
  sm[t] = (t < N) ? rowptr[t + 1] : 0;
  __syncthreads();
  for (int off = 1; off < 1024; off <<= 1) {
    int v = sm[t];
    int a = (t >= off) ? sm[t - off] : 0;
    __syncthreads();
    sm[t] = v + a;
    __syncthreads();
  }
  if (t < N) rowptr[t + 1] = sm[t];
  if (t == 0) rowptr[0] = 0;
}

__global__ __launch_bounds__(256) void k_fill(const float* __restrict__ S,
                                              const int* __restrict__ rowptr,
                                              int* __restrict__ cols,
                                              float* __restrict__ vals) {
  int lane = threadIdx.x & 63;
  int m = blockIdx.x * 4 + (threadIdx.x >> 6);
  int base = rowptr[m];
  for (int n0 = 0; n0 < N; n0 += 64) {
    int n = n0 + lane;
    float v = (n < N) ? S[m * N + n] : 0.f;
    bool nz = (v != 0.f);
    unsigned long long mask = __ballot(nz);
    int pos = base + (int)__popcll(mask & ((1ull << lane) - 1ull));
    if (nz && pos < CSR_CAP) { cols[pos] = n; vals[pos] = v; }
    base += (int)__popcll(mask);
  }
}

// ---------------- sparse S-multiply ----------------
// out = S @ in            (CHEB=0)
// out = 2*(S @ in) - sub  (CHEB=1)
// h-part: (B*N,64) rows; scalar part has per-batch stride (so `inputs` can be
// read in place with stride T*N, or a zero buffer with stride 0).

template <int CHEB>
__global__ __launch_bounds__(256) void k_spmv(
    const int* __restrict__ rowptr, const int* __restrict__ cols,
    const float* __restrict__ vals,
    const float* __restrict__ in_h, const float* __restrict__ in_s, int in_sst,
    const float* __restrict__ sub_h, const float* __restrict__ sub_s, int sub_sst,
    float* __restrict__ out_h, float* __restrict__ out_s) {
  int lane = threadIdx.x & 63;
  int m = blockIdx.x * 4 + (threadIdx.x >> 6);
  int b = blockIdx.y;
  int s = rowptr[m], e = rowptr[m + 1];
  int base = b * N;
  float acc = 0.f, accs = 0.f;
  for (int j = s; j < e; ++j) {
    float v = vals[j];
    int c = cols[j];
    acc  += v * in_h[(base + c) * 64 + lane];
    accs += v * in_s[b * in_sst + c];      // uniform across wave -> scalar path
  }
  int r = base + m;
  if (CHEB) {
    out_h[r * 64 + lane] = 2.f * acc - sub_h[r * 64 + lane];
    if (lane == 0) out_s[r] = 2.f * accs - sub_s[b * sub_sst + m];
  } else {
    out_h[r * 64 + lane] = acc;
    if (lane == 0) out_s[r] = accs;
  }
}

// ---------------- gconv weight GEMM ----------------
// y[r,o] = sum_f sum_k xs_k[r,f] * W[f*3+k, o]   (f=0 scalar part, f=1..64 h part)
// EPI=0: sigmoid; blockIdx.y==0 (r-gate)  -> x0ch[r,o] = sig * h[r,o]
//                 blockIdx.y==1 (u-gate)  -> ubuf[r,o] = sig
// EPI=1: c = tanh(y); h[r,o] = u*h + (1-u)*c   (fused GRU update)

template <int EPI>
__global__ __launch_bounds__(256) void k_gemm(
    const float* __restrict__ a0h, const float* __restrict__ a0s, int a0sst,
    const float* __restrict__ a1h, const float* __restrict__ a1s,
    const float* __restrict__ a2h, const float* __restrict__ a2s,
    const float* __restrict__ W, const float* __restrict__ bias, int wstride,
    float* __restrict__ outA, float* __restrict__ outB,
    const float* __restrict__ ubuf, float* __restrict__ h) {
  __shared__ float Wl[FK * 64];
  const int ob = blockIdx.y * 64;
  for (int i = threadIdx.x; i < FK * 64; i += 256) {
    int k = i >> 6, o = i & 63;
    Wl[i] = W[k * wstride + ob + o];
  }
  __syncthreads();

  const int tx = threadIdx.x & 7, ty = threadIdx.x >> 3;
  const int o0 = tx * 8;
  const int r0 = blockIdx.x * 128 + ty * 4;

  float acc[4][8];
#pragma unroll
  for (int rr = 0; rr < 4; ++rr)
#pragma unroll
    for (int o = 0; o < 8; ++o) acc[rr][o] = 0.f;

  // f = 0 (scalar features, W rows 0..2)
  {
    float w0[8], w1[8], w2[8];
#pragma unroll
    for (int o = 0; o < 8; ++o) {
      w0[o] = Wl[0 * 64 + o0 + o];
      w1[o] = Wl[1 * 64 + o0 + o];
      w2[o] = Wl[2 * 64 + o0 + o];
    }
#pragma unroll
    for (int rr = 0; rr < 4; ++rr) {
      int r = r0 + rr;
      int b = r / N, n = r - b * N;
      float a0 = a0s[b * a0sst + n];
      float a1 = a1s[r];
      float a2 = a2s[r];
#pragma unroll
      for (int o = 0; o < 8; ++o)
        acc[rr][o] += a0 * w0[o] + a1 * w1[o] + a2 * w2[o];
    }
  }

  // f = 1..64 (h features), chunks of 4
  for (int hf = 0; hf < 64; hf += 4) {
    float4 A0[4], A1[4], A2[4];
#pragma unroll
    for (int rr = 0; rr < 4; ++rr) {
      int idx = (r0 + rr) * 64 + hf;
      A0[rr] = *(const float4*)&a0h[idx];
      A1[rr] = *(const float4*)&a1h[idx];
      A2[rr] = *(const float4*)&a2h[idx];
    }
#pragma unroll
    for (int ff = 0; ff < 4; ++ff) {
      int k3 = (hf + ff + 1) * 3;
      float w0[8], w1[8], w2[8];
#pragma unroll
      for (int o = 0; o < 8; ++o) {
        w0[o] = Wl[(k3 + 0) * 64 + o0 + o];
        w1[o] = Wl[(k3 + 1) * 64 + o0 + o];
        w2[o] = Wl[(k3 + 2) * 64 + o0 + o];
      }
#pragma unroll
      for (int rr = 0; rr < 4; ++rr) {
        float a0 = ((const float*)&A0[rr])[ff];
        float a1 = ((const float*)&A1[rr])[ff];
        float a2 = ((const float*)&A2[rr])[ff];
#pragma unroll
        for (int o = 0; o < 8; ++o)
          acc[rr][o] += a0 * w0[o] + a1 * w1[o] + a2 * w2[o];
      }
    }
  }

  // epilogue
#pragma unroll
  for (int rr = 0; rr < 4; ++rr) {
    int r = r0 + rr;
#pragma unroll
    for (int o = 0; o < 8; ++o) {
      float v = acc[rr][o] + bias[ob + o0 + o];
      int i64 = r * 64 + o0 + o;
      if (EPI == 0) {
        float sig = 1.f / (1.f + expf(-v));
        if (ob == 0) outA[i64] = sig * h[i64];   // x0ch = r .* h
        else         outB[i64] = sig;            // u gate
      } else {
        float cv = tanhf(v);
        float u = ubuf[i64];
        h[i64] = u * h[i64] + (1.f - u) * cv;
      }
    }
  }
}

// ---------------- final projection ----------------

__global__ __launch_bounds__(256) void k_proj(const float* __restrict__ h,
                                              const float* __restrict__ Wp,
                                              const float* __restrict__ bp,
                                              float* __restrict__ out) {
  int lane = threadIdx.x & 63;
  int r = blockIdx.x * 4 + (threadIdx.x >> 6);
  float p = h[r * 64 + lane] * Wp[lane];
  for (int off = 32; off; off >>= 1) p += __shfl_down(p, off, 64);
  if (lane == 0) out[r] = p + bp[0];
}

// ---------------- host launch ----------------

extern "C" void kernel_launch(void* const* d_in, const int* in_sizes, int n_in,
                              void* d_out, int out_size, void* d_ws, size_t ws_size,
                              hipStream_t stream) {
  const float* inp  = (const float*)d_in[0];
  const float* S    = (const float*)d_in[1];
  const float* eWru = (const float*)d_in[2];
  const float* ebru = (const float*)d_in[3];
  const float* eWc  = (const float*)d_in[4];
  const float* ebc  = (const float*)d_in[5];
  const float* dWru = (const float*)d_in[6];
  const float* dbru = (const float*)d_in[7];
  const float* dWc  = (const float*)d_in[8];
  const float* dbc  = (const float*)d_in[9];
  const float* Wp   = (const float*)d_in[10];
  const float* bp   = (const float*)d_in[11];
  float* out = (float*)d_out;

  float* ws = (float*)d_ws;
  float* h    = ws; ws += (size_t)R * U;     // 4.096M
  float* zbuf = ws; ws += 1024;              // zero scalar row
  float* x1s  = ws; ws += R;
  float* x2s  = ws; ws += R;
  float* x1h  = ws; ws += (size_t)R * U;
  float* x2h  = ws; ws += (size_t)R * U;
  float* x0ch = ws; ws += (size_t)R * U;     // r .* h
  float* ubuf = ws; ws += (size_t)R * U;     // u gate
  int*   rowptr = (int*)ws;
  int*   cols   = rowptr + 1024;
  float* vals   = (float*)(cols + CSR_CAP);

  hipMemsetAsync(h, 0, (size_t)R * U * sizeof(float), stream);
  hipMemsetAsync(zbuf, 0, 1024 * sizeof(float), stream);

  k_count<<<250, 256, 0, stream>>>(S, rowptr);
  k_scan<<<1, 1024, 0, stream>>>(rowptr);
  k_fill<<<250, 256, 0, stream>>>(S, rowptr, cols, vals);

  dim3 gs(250, 64);

  auto cell = [&](const float* xs, int xst, const float* Wru, const float* bru,
                  const float* Wc, const float* bc) {
    // gconv 1: x0 = [x | h]
    k_spmv<0><<<gs, 256, 0, stream>>>(rowptr, cols, vals,
                                      h, xs, xst, nullptr, nullptr, 0, x1h, x1s);
    k_spmv<1><<<gs, 256, 0, stream>>>(rowptr, cols, vals,
                                      x1h, x1s, N, h, xs, xst, x2h, x2s);
    k_gemm<0><<<dim3(500, 2), 256, 0, stream>>>(h, xs, xst, x1h, x1s, x2h, x2s,
                                                Wru, bru, 2 * U,
                                                x0ch, ubuf, nullptr, h);
    // gconv 2: x0 = [x | r.*h]
    k_spmv<0><<<gs, 256, 0, stream>>>(rowptr, cols, vals,
                                      x0ch, xs, xst, nullptr, nullptr, 0, x1h, x1s);
    k_spmv<1><<<gs, 256, 0, stream>>>(rowptr, cols, vals,
                                      x1h, x1s, N, x0ch, xs, xst, x2h, x2s);
    k_gemm<1><<<dim3(500, 1), 256, 0, stream>>>(x0ch, xs, xst, x1h, x1s, x2h, x2s,
                                                Wc, bc, U,
                                                nullptr, nullptr, ubuf, h);
  };

  for (int t = 0; t < T; ++t)
    cell(inp + t * N, T * N, eWru, ebru, eWc, ebc);   // encoder
  cell(zbuf, 0, dWru, dbru, dWc, dbc);                // decoder (GO = zeros)

  k_proj<<<16000, 256, 0, stream>>>(h, Wp, bp, out);
  (void)in_sizes; (void)n_in; (void)out_size; (void)ws_size;
}

// Round 2
// 2734.941 us; speedup vs baseline: 2.0676x; 2.0676x over previous
//
#include <hip/hip_runtime.h>
#include <hip/hip_bf16.h>

namespace {
constexpr int B  = 64;
constexpr int T  = 8;
constexpr int N  = 1000;
constexpr int U  = 64;
constexpr int FK = 195;          // F*K = 65*3
constexpr int R  = B * N;        // 64000 rows
constexpr int VW = B * U;        // 4096 floats per node (h-part vector)
constexpr int CSR_CAP = 65536;
}

// ---------------- CSR build (deterministic, no atomics) ----------------

__global__ __launch_bounds__(256) void k_count(const float* __restrict__ S,
                                               int* __restrict__ rowptr) {
  int lane = threadIdx.x & 63;
  int m = blockIdx.x * 4 + (threadIdx.x >> 6);   // 250 blocks * 4 rows = 1000
  int c = 0;
  for (int n = lane; n < N; n += 64) c += (S[m * N + n] != 0.f) ? 1 : 0;
  for (int off = 32; off; off >>= 1) c += __shfl_down(c, off, 64);
  if (lane == 0) rowptr[m + 1] = c;
}

__global__ __launch_bounds__(1024) void k_scan(int* __restrict__ rowptr) {
  __shared__ int sm[1024];
  int t = threadIdx.x;
  sm[t] = (t < N) ? rowptr[t + 1] : 0;
  __syncthreads();
  for (int off = 1; off < 1024; off <<= 1) {
    int v = sm[t];
    int a = (t >= off) ? sm[t - off] : 0;
    __syncthreads();
    sm[t] = v + a;
    __syncthreads();
  }
  if (t < N) rowptr[t + 1] = sm[t];
  if (t == 0) rowptr[0] = 0;
}

__global__ __launch_bounds__(256) void k_fill(const float* __restrict__ S,
                                              const int* __restrict__ rowptr,
                                              int* __restrict__ cols,
                                              float* __restrict__ vals) {
  int lane = threadIdx.x & 63;
  int m = blockIdx.x * 4 + (threadIdx.x >> 6);
  int base = rowptr[m];
  for (int n0 = 0; n0 < N; n0 += 64) {
    int n = n0 + lane;
    float v = (n < N) ? S[m * N + n] : 0.f;
    bool nz = (v != 0.f);
    unsigned long long mask = __ballot(nz);
    int pos = base + (int)__popcll(mask & ((1ull << lane) - 1ull));
    if (nz && pos < CSR_CAP) { cols[pos] = n; vals[pos] = v; }
    base += (int)__popcll(mask);
  }
}

// ---------------- inputs transpose: (B,T,N) -> (T,N,B) ----------------

__global__ __launch_bounds__(256) void k_xt(const float* __restrict__ inp,
                                            float* __restrict__ xT) {
  __shared__ float tile[64][65];
  const int t  = blockIdx.y;
  const int n0 = blockIdx.x * 64;
  const int lx = threadIdx.x & 63;
  const int ly = threadIdx.x >> 6;
  for (int bb = ly; bb < 64; bb += 4) {
    int n = n0 + lx;
    tile[bb][lx] = (n < N) ? inp[(bb * T + t) * N + n] : 0.f;
  }
  __syncthreads();
  for (int nn = ly; nn < 64; nn += 4) {
    int n = n0 + nn;
    if (n < N) xT[((size_t)t * N + n) * 64 + lx] = tile[lx][nn];
  }
}

// ---------------- sparse S-multiply, (n, b*u) layout ----------------
// h-part:  in_h (N, 4096);  out_h[m] = { S@in | 2*S@in - sub }
// scalar:  in_s (N, 64);    same recurrence, handled by blockIdx.y==4
// All scalar arrays are [n*64 + b]; a persistent zero buffer stands in for
// the decoder's GO-symbol zeros.

template <int CHEB>
__global__ __launch_bounds__(256) void k_spmv(
    const int* __restrict__ rowptr, const int* __restrict__ cols,
    const float* __restrict__ vals,
    const float* __restrict__ in_h, const float* __restrict__ in_s,
    const float* __restrict__ sub_h, const float* __restrict__ sub_s,
    float* __restrict__ out_h, float* __restrict__ out_s) {
  const int m = blockIdx.x;
  const int s = rowptr[m], e = rowptr[m + 1];

  if (blockIdx.y == 4) {                     // scalar part (64 lanes active)
    if (threadIdx.x >= 64) return;
    const int b = threadIdx.x;
    float acc = 0.f;
    for (int j = s; j < e; ++j) acc = fmaf(vals[j], in_s[cols[j] * 64 + b], acc);
    if (CHEB) out_s[m * 64 + b] = 2.f * acc - sub_s[m * 64 + b];
    else      out_s[m * 64 + b] = acc;
    return;
  }

  const int off = blockIdx.y * 1024 + threadIdx.x * 4;
  const float* __restrict__ base = in_h + off;
  float4 acc = make_float4(0.f, 0.f, 0.f, 0.f);

  int j = s;
  for (; j + 3 < e; j += 4) {
    int   c0 = cols[j],     c1 = cols[j + 1], c2 = cols[j + 2], c3 = cols[j + 3];
    float v0 = vals[j],     v1 = vals[j + 1], v2 = vals[j + 2], v3 = vals[j + 3];
    float4 a0 = *(const float4*)(base + (size_t)c0 * VW);
    float4 a1 = *(const float4*)(base + (size_t)c1 * VW);
    float4 a2 = *(const float4*)(base + (size_t)c2 * VW);
    float4 a3 = *(const float4*)(base + (size_t)c3 * VW);
    acc.x = fmaf(v0, a0.x, acc.x); acc.y = fmaf(v0, a0.y, acc.y);
    acc.z = fmaf(v0, a0.z, acc.z); acc.w = fmaf(v0, a0.w, acc.w);
    acc.x = fmaf(v1, a1.x, acc.x); acc.y = fmaf(v1, a1.y, acc.y);
    acc.z = fmaf(v1, a1.z, acc.z); acc.w = fmaf(v1, a1.w, acc.w);
    acc.x = fmaf(v2, a2.x, acc.x); acc.y = fmaf(v2, a2.y, acc.y);
    acc.z = fmaf(v2, a2.z, acc.z); acc.w = fmaf(v2, a2.w, acc.w);
    acc.x = fmaf(v3, a3.x, acc.x); acc.y = fmaf(v3, a3.y, acc.y);
    acc.z = fmaf(v3, a3.z, acc.z); acc.w = fmaf(v3, a3.w, acc.w);
  }
  for (; j < e; ++j) {
    float v = vals[j];
    float4 a = *(const float4*)(base + (size_t)cols[j] * VW);
    acc.x = fmaf(v, a.x, acc.x); acc.y = fmaf(v, a.y, acc.y);
    acc.z = fmaf(v, a.z, acc.z); acc.w = fmaf(v, a.w, acc.w);
  }

  const size_t oi = (size_t)m * VW + off;
  if (CHEB) {
    float4 sb = *(const float4*)(sub_h + oi);
    float4 r;
    r.x = 2.f * acc.x - sb.x; r.y = 2.f * acc.y - sb.y;
    r.z = 2.f * acc.z - sb.z; r.w = 2.f * acc.w - sb.w;
    *(float4*)(out_h + oi) = r;
  } else {
    *(float4*)(out_h + oi) = acc;
  }
}

// ---------------- gconv weight GEMM ----------------
// rows r = n*64 + b.  y[r,o] = sum_f sum_k xs_k[r,f] * W[f*3+k, o]
// EPI=0: sigmoid; blockIdx.y==0 (r-gate)  -> x0ch[r,o] = sig * h[r,o]
//                 blockIdx.y==1 (u-gate)  -> ubuf[r,o] = sig
// EPI=1: c = tanh(y); h[r,o] = u*h + (1-u)*c   (fused GRU update)

template <int EPI>
__global__ __launch_bounds__(256) void k_gemm(
    const float* __restrict__ a0h, const float* __restrict__ a0s,
    const float* __restrict__ a1h, const float* __restrict__ a1s,
    const float* __restrict__ a2h, const float* __restrict__ a2s,
    const float* __restrict__ W, const float* __restrict__ bias, int wstride,
    float* __restrict__ outA, float* __restrict__ outB,
    const float* __restrict__ ubuf, float* __restrict__ h) {
  __shared__ float Wl[FK * 64];
  const int ob = blockIdx.y * 64;
  for (int i = threadIdx.x; i < FK * 64; i += 256) {
    int k = i >> 6, o = i & 63;
    Wl[i] = W[k * wstride + ob + o];
  }
  __syncthreads();

  const int tx = threadIdx.x & 7, ty = threadIdx.x >> 3;
  const int o0 = tx * 8;
  const int r0 = blockIdx.x * 128 + ty * 4;

  float acc[4][8];
#pragma unroll
  for (int rr = 0; rr < 4; ++rr)
#pragma unroll
    for (int o = 0; o < 8; ++o) acc[rr][o] = 0.f;

  // f = 0 (scalar features, W rows 0..2)
  {
    float w0[8], w1[8], w2[8];
#pragma unroll
    for (int o = 0; o < 8; ++o) {
      w0[o] = Wl[0 * 64 + o0 + o];
      w1[o] = Wl[1 * 64 + o0 + o];
      w2[o] = Wl[2 * 64 + o0 + o];
    }
    float4 A0 = *(const float4*)&a0s[r0];
    float4 A1 = *(const float4*)&a1s[r0];
    float4 A2 = *(const float4*)&a2s[r0];
#pragma unroll
    for (int rr = 0; rr < 4; ++rr) {
      float a0 = ((const float*)&A0)[rr];
      float a1 = ((const float*)&A1)[rr];
      float a2 = ((const float*)&A2)[rr];
#pragma unroll
      for (int o = 0; o < 8; ++o)
        acc[rr][o] += a0 * w0[o] + a1 * w1[o] + a2 * w2[o];
    }
  }

  // f = 1..64 (h features), chunks of 4
  for (int hf = 0; hf < 64; hf += 4) {
    float4 A0[4], A1[4], A2[4];
#pragma unroll
    for (int rr = 0; rr < 4; ++rr) {
      int idx = (r0 + rr) * 64 + hf;
      A0[rr] = *(const float4*)&a0h[idx];
      A1[rr] = *(const float4*)&a1h[idx];
      A2[rr] = *(const float4*)&a2h[idx];
    }
#pragma unroll
    for (int ff = 0; ff < 4; ++ff) {
      int k3 = (hf + ff + 1) * 3;
      float w0[8], w1[8], w2[8];
#pragma unroll
      for (int o = 0; o < 8; ++o) {
        w0[o] = Wl[(k3 + 0) * 64 + o0 + o];
        w1[o] = Wl[(k3 + 1) * 64 + o0 + o];
        w2[o] = Wl[(k3 + 2) * 64 + o0 + o];
      }
#pragma unroll
      for (int rr = 0; rr < 4; ++rr) {
        float a0 = ((const float*)&A0[rr])[ff];
        float a1 = ((const float*)&A1[rr])[ff];
        float a2 = ((const float*)&A2[rr])[ff];
#pragma unroll
        for (int o = 0; o < 8; ++o)
          acc[rr][o] += a0 * w0[o] + a1 * w1[o] + a2 * w2[o];
      }
    }
  }

  // epilogue
#pragma unroll
  for (int rr = 0; rr < 4; ++rr) {
    int r = r0 + rr;
#pragma unroll
    for (int o = 0; o < 8; ++o) {
      float v = acc[rr][o] + bias[ob + o0 + o];
      int i64 = r * 64 + o0 + o;
      if (EPI == 0) {
        float sig = 1.f / (1.f + expf(-v));
        if (ob == 0) outA[i64] = sig * h[i64];   // x0ch = r .* h
        else         outB[i64] = sig;            // u gate
      } else {
        float cv = tanhf(v);
        float u = ubuf[i64];
        h[i64] = u * h[i64] + (1.f - u) * cv;
      }
    }
  }
}

// ---------------- final projection ----------------

__global__ __launch_bounds__(256) void k_proj(const float* __restrict__ h,
                                              const float* __restrict__ Wp,
                                              const float* __restrict__ bp,
                                              float* __restrict__ out) {
  int lane = threadIdx.x & 63;
  int r = blockIdx.x * 4 + (threadIdx.x >> 6);
  float p = h[r * 64 + lane] * Wp[lane];
  for (int off = 32; off; off >>= 1) p += __shfl_down(p, off, 64);
  if (lane == 0) {
    int n = r >> 6, b = r & 63;
    out[b * N + n] = p + bp[0];
  }
}

// ---------------- host launch ----------------

extern "C" void kernel_launch(void* const* d_in, const int* in_sizes, int n_in,
                              void* d_out, int out_size, void* d_ws, size_t ws_size,
                              hipStream_t stream) {
  const float* inp  = (const float*)d_in[0];
  const float* S    = (const float*)d_in[1];
  const float* eWru = (const float*)d_in[2];
  const float* ebru = (const float*)d_in[3];
  const float* eWc  = (const float*)d_in[4];
  const float* ebc  = (const float*)d_in[5];
  const float* dWru = (const float*)d_in[6];
  const float* dbru = (const float*)d_in[7];
  const float* dWc  = (const float*)d_in[8];
  const float* dbc  = (const float*)d_in[9];
  const float* Wp   = (const float*)d_in[10];
  const float* bp   = (const float*)d_in[11];
  float* out = (float*)d_out;

  float* ws = (float*)d_ws;
  float* h    = ws; ws += (size_t)R * U;     // (N,B,U)
  float* x1h  = ws; ws += (size_t)R * U;
  float* x2h  = ws; ws += (size_t)R * U;
  float* x0ch = ws; ws += (size_t)R * U;     // r .* h
  float* ubuf = ws; ws += (size_t)R * U;     // u gate
  float* x1s  = ws; ws += 65536;             // (N,B)
  float* x2s  = ws; ws += 65536;
  float* xT   = ws; ws += 524288;            // (T,N,B)
  float* zNB  = ws; ws += 65536;             // zeros (N,B)
  int*   rowptr = (int*)ws;
  int*   cols   = rowptr + 1024;
  float* vals   = (float*)(cols + CSR_CAP);

  hipMemsetAsync(h, 0, (size_t)R * U * sizeof(float), stream);
  hipMemsetAsync(zNB, 0, 65536 * sizeof(float), stream);

  k_count<<<250, 256, 0, stream>>>(S, rowptr);
  k_scan<<<1, 1024, 0, stream>>>(rowptr);
  k_fill<<<250, 256, 0, stream>>>(S, rowptr, cols, vals);
  k_xt<<<dim3(16, T), 256, 0, stream>>>(inp, xT);

  dim3 gs(N, 5);

  auto cell = [&](const float* xs, const float* Wru, const float* bru,
                  const float* Wc, const float* bc) {
    // gconv 1: x0 = [x | h]
    k_spmv<0><<<gs, 256, 0, stream>>>(rowptr, cols, vals,
                                      h, xs, nullptr, nullptr, x1h, x1s);
    k_spmv<1><<<gs, 256, 0, stream>>>(rowptr, cols, vals,
                                      x1h, x1s, h, xs, x2h, x2s);
    k_gemm<0><<<dim3(500, 2), 256, 0, stream>>>(h, xs, x1h, x1s, x2h, x2s,
                                                Wru, bru, 2 * U,
                                                x0ch, ubuf, nullptr, h);
    // gconv 2: x0 = [x | r.*h]
    k_spmv<0><<<gs, 256, 0, stream>>>(rowptr, cols, vals,
                                      x0ch, xs, nullptr, nullptr, x1h, x1s);
    k_spmv<1><<<gs, 256, 0, stream>>>(rowptr, cols, vals,
                                      x1h, x1s, x0ch, xs, x2h, x2s);
    k_gemm<1><<<dim3(500, 1), 256, 0, stream>>>(x0ch, xs, x1h, x1s, x2h, x2s,
                                                Wc, bc, U,
                                                nullptr, nullptr, ubuf, h);
  };

  for (int t = 0; t < T; ++t)
    cell(xT + (size_t)t * N * B, eWru, ebru, eWc, ebc);   // encoder
  cell(zNB, dWru, dbru, dWc, dbc);                        // decoder (GO = zeros)

  k_proj<<<16000, 256, 0, stream>>>(h, Wp, bp, out);
  (void)in_sizes; (void)n_in; (void)out_size; (void)ws_size;
}

// Round 3
// 1405.467 us; speedup vs baseline: 4.0234x; 1.9459x over previous
//
#include <hip/hip_runtime.h>
#include <hip/hip_bf16.h>

namespace {
constexpr int B  = 64;
constexpr int T  = 8;
constexpr int N  = 1000;
constexpr int U  = 64;
constexpr int R  = B * N;        // 64000 rows (r = n*64 + b)
constexpr int RS = 224;          // padded K / row stride of A buffers
constexpr int CSR_CAP = 65536;
}

typedef short bf16x8 __attribute__((ext_vector_type(8)));
typedef float f32x4  __attribute__((ext_vector_type(4)));
typedef unsigned short u16;

__device__ __forceinline__ float bf2f(u16 x) {
  unsigned u = ((unsigned)x) << 16;
  float f; __builtin_memcpy(&f, &u, 4); return f;
}
__device__ __forceinline__ u16 f2bf(float f) {
  unsigned u; __builtin_memcpy(&u, &f, 4);
  u += 0x7FFFu + ((u >> 16) & 1u);
  return (u16)(u >> 16);
}

// ---------------- CSR build (deterministic, no atomics) ----------------

__global__ __launch_bounds__(256) void k_count(const float* __restrict__ S,
                                               int* __restrict__ rowptr) {
  int lane = threadIdx.x & 63;
  int m = blockIdx.x * 4 + (threadIdx.x >> 6);
  int c = 0;
  for (int n = lane; n < N; n += 64) c += (S[m * N + n] != 0.f) ? 1 : 0;
  for (int off = 32; off; off >>= 1) c += __shfl_down(c, off, 64);
  if (lane == 0) rowptr[m + 1] = c;
}

__global__ __launch_bounds__(1024) void k_scan(int* __restrict__ rowptr) {
  __shared__ int sm[1024];
  int t = threadIdx.x;
  sm[t] = (t < N) ? rowptr[t + 1] : 0;
  __syncthreads();
  for (int off = 1; off < 1024; off <<= 1) {
    int v = sm[t];
    int a = (t >= off) ? sm[t - off] : 0;
    __syncthreads();
    sm[t] = v + a;
    __syncthreads();
  }
  if (t < N) rowptr[t + 1] = sm[t];
  if (t == 0) rowptr[0] = 0;
}

__global__ __launch_bounds__(256) void k_fill(const float* __restrict__ S,
                                              const int* __restrict__ rowptr,
                                              int* __restrict__ cols,
                                              float* __restrict__ vals) {
  int lane = threadIdx.x & 63;
  int m = blockIdx.x * 4 + (threadIdx.x >> 6);
  int base = rowptr[m];
  for (int n0 = 0; n0 < N; n0 += 64) {
    int n = n0 + lane;
    float v = (n < N) ? S[m * N + n] : 0.f;
    bool nz = (v != 0.f);
    unsigned long long mask = __ballot(nz);
    int pos = base + (int)__popcll(mask & ((1ull << lane) - 1ull));
    if (nz && pos < CSR_CAP) { cols[pos] = n; vals[pos] = v; }
    base += (int)__popcll(mask);
  }
}

// ---------------- inputs transpose: (B,T,N) -> Xt[t][n*64+b] fp32 ----------

__global__ __launch_bounds__(256) void k_xt(const float* __restrict__ inp,
                                            float* __restrict__ xT) {
  __shared__ float tile[64][65];
  const int t  = blockIdx.y;
  const int n0 = blockIdx.x * 64;
  const int lx = threadIdx.x & 63;
  const int ly = threadIdx.x >> 6;
  for (int bb = ly; bb < 64; bb += 4) {
    int n = n0 + lx;
    tile[bb][lx] = (n < N) ? inp[(bb * T + t) * N + n] : 0.f;
  }
  __syncthreads();
  for (int nn = ly; nn < 64; nn += 4) {
    int n = n0 + nn;
    if (n < N) xT[((size_t)t * N + n) * 64 + lx] = tile[lx][nn];
  }
}

// ---------------- scalar Chebyshev chain (fp32, all timesteps) -------------

__global__ __launch_bounds__(64) void k_sspmv(const int* __restrict__ rowptr,
                                              const int* __restrict__ cols,
                                              const float* __restrict__ vals,
                                              const float* __restrict__ in,
                                              const float* __restrict__ sub,
                                              float* __restrict__ out, int cheb) {
  const int m = blockIdx.x, b = threadIdx.x;
  const size_t toff = (size_t)blockIdx.y * R;
  float acc = 0.f;
  for (int j = rowptr[m]; j < rowptr[m + 1]; ++j)
    acc = fmaf(vals[j], in[toff + cols[j] * 64 + b], acc);
  if (cheb) acc = 2.f * acc - sub[toff + m * 64 + b];
  out[toff + m * 64 + b] = acc;
}

// ---------------- W transpose+reorder -> Wt[o][224] bf16 -------------------
// kp<192: original row ((kp&63)+1)*3 + (kp>>6);  192..194: row kp-192; else 0.

__global__ __launch_bounds__(256) void k_wprep(
    const float* __restrict__ w0, const float* __restrict__ w1,
    const float* __restrict__ w2, const float* __restrict__ w3,
    u16* __restrict__ o0, u16* __restrict__ o1,
    u16* __restrict__ o2, u16* __restrict__ o3) {
  const float* W; u16* O; int ncol;
  switch (blockIdx.y) {
    case 0:  W = w0; O = o0; ncol = 128; break;
    case 1:  W = w1; O = o1; ncol = 64;  break;
    case 2:  W = w2; O = o2; ncol = 128; break;
    default: W = w3; O = o3; ncol = 64;  break;
  }
  int idx = blockIdx.x * 256 + threadIdx.x;
  if (idx >= ncol * RS) return;
  int o = idx / RS, kp = idx - o * RS;
  float v = 0.f;
  if (kp < 192)      v = W[(((kp & 63) + 1) * 3 + (kp >> 6)) * ncol + o];
  else if (kp < 195) v = W[(kp - 192) * ncol + o];
  O[idx] = f2bf(v);
}

// ---------------- bf16 diffusion spmv over one 64-col segment --------------
// block = node m; thread (b = tid>>2, ch = tid&3) owns 16 bf16 at col ch*16.
// out = S@in (sub==null) or 2*S@in - sub. Optionally writes scalar slots
// (cols 192..194) of both A buffers: xmode 0 none, 1 from xs*, 2 zeros.

__global__ __launch_bounds__(256) void k_spmvb(
    const int* __restrict__ rowptr, const int* __restrict__ cols,
    const float* __restrict__ vals,
    const u16* __restrict__ in, const u16* __restrict__ sub,
    u16* __restrict__ out,
    const float* __restrict__ xs0, const float* __restrict__ xs1,
    const float* __restrict__ xs2,
    u16* __restrict__ scA, u16* __restrict__ scB, int xmode) {
  const int m = blockIdx.x;
  const int b = threadIdx.x >> 2, ch = threadIdx.x & 3;
  const int col = ch * 16;
  const int s = rowptr[m], e = rowptr[m + 1];
  float acc[16];
#pragma unroll
  for (int i = 0; i < 16; ++i) acc[i] = 0.f;

  for (int j = s; j < e; ++j) {
    const float v = vals[j];
    const u16* p = in + ((size_t)cols[j] * 64 + b) * RS + col;
    bf16x8 q0 = *(const bf16x8*)p;
    bf16x8 q1 = *(const bf16x8*)(p + 8);
#pragma unroll
    for (int i = 0; i < 8; ++i) acc[i]     = fmaf(v, bf2f((u16)q0[i]), acc[i]);
#pragma unroll
    for (int i = 0; i < 8; ++i) acc[i + 8] = fmaf(v, bf2f((u16)q1[i]), acc[i + 8]);
  }

  const size_t ro = ((size_t)m * 64 + b) * RS + col;
  if (sub) {
    bf16x8 s0 = *(const bf16x8*)(sub + ro);
    bf16x8 s1 = *(const bf16x8*)(sub + ro + 8);
#pragma unroll
    for (int i = 0; i < 8; ++i) acc[i]     = 2.f * acc[i]     - bf2f((u16)s0[i]);
#pragma unroll
    for (int i = 0; i < 8; ++i) acc[i + 8] = 2.f * acc[i + 8] - bf2f((u16)s1[i]);
  }
  bf16x8 o0, o1;
#pragma unroll
  for (int i = 0; i < 8; ++i) { o0[i] = (short)f2bf(acc[i]); o1[i] = (short)f2bf(acc[i + 8]); }
  *(bf16x8*)(out + ro) = o0;
  *(bf16x8*)(out + ro + 8) = o1;

  if (xmode && ch == 0) {
    const int r = m * 64 + b;
    u16 s0v = 0, s1v = 0, s2v = 0;
    if (xmode == 1) { s0v = f2bf(xs0[r]); s1v = f2bf(xs1[r]); s2v = f2bf(xs2[r]); }
    const size_t o = (size_t)r * RS + 192;
    scA[o] = s0v; scA[o + 1] = s1v; scA[o + 2] = s2v;
    scB[o] = s0v; scB[o + 1] = s1v; scB[o + 2] = s2v;
  }
}

// ---------------- MFMA GEMM: (64000 x 224) x (224 x NCOL) ------------------
// EPI=0 (NCOL=128, ru): sig = sigmoid(y+b); col<64 -> outA seg0 = bf16(sig*h)
//                       col>=64 -> ubuf = bf16(sig)
// EPI=1 (NCOL=64, c):   c = tanh(y+b); hn = u*h+(1-u)*c; hbuf=hn (fp32),
//                       outA seg0 = bf16(hn)

template <int EPI>
__global__ __launch_bounds__(256) void k_mgemm(
    const u16* __restrict__ A, const u16* __restrict__ Wt,
    const float* __restrict__ bias,
    u16* __restrict__ outA, u16* __restrict__ ubuf,
    float* __restrict__ hbuf) {
  constexpr int NF = EPI ? 4 : 8;
  const int l  = threadIdx.x & 63;
  const int wv = threadIdx.x >> 6;
  const int lr = l & 15, lk = l >> 4;
  const int r0 = blockIdx.x * 128 + wv * 32;

  f32x4 acc[2][NF];
#pragma unroll
  for (int i = 0; i < 2; ++i)
#pragma unroll
    for (int j = 0; j < NF; ++j) acc[i][j] = (f32x4){0.f, 0.f, 0.f, 0.f};

  const u16* pa0 = A + (size_t)(r0 + lr) * RS + lk * 8;
  const u16* pa1 = pa0 + 16 * RS;
  const u16* pw  = Wt + (size_t)lr * RS + lk * 8;

#pragma unroll
  for (int ks = 0; ks < 7; ++ks) {
    bf16x8 a0 = *(const bf16x8*)(pa0 + ks * 32);
    bf16x8 a1 = *(const bf16x8*)(pa1 + ks * 32);
#pragma unroll
    for (int cb = 0; cb < NF; ++cb) {
      bf16x8 bb = *(const bf16x8*)(pw + (size_t)cb * (16 * RS) + ks * 32);
      acc[0][cb] = __builtin_amdgcn_mfma_f32_16x16x32_bf16(a0, bb, acc[0][cb], 0, 0, 0);
      acc[1][cb] = __builtin_amdgcn_mfma_f32_16x16x32_bf16(a1, bb, acc[1][cb], 0, 0, 0);
    }
  }

#pragma unroll
  for (int mf = 0; mf < 2; ++mf)
#pragma unroll
    for (int cb = 0; cb < NF; ++cb) {
      const int col = cb * 16 + lr;
      const float bs = bias[col];
#pragma unroll
      for (int j = 0; j < 4; ++j) {
        const int row = r0 + mf * 16 + lk * 4 + j;
        const float v = acc[mf][cb][j] + bs;
        if (EPI == 0) {
          const float sig = 1.f / (1.f + expf(-v));
          if (col < 64)
            outA[(size_t)row * RS + col] = f2bf(sig * hbuf[(size_t)row * 64 + col]);
          else
            ubuf[(size_t)row * 64 + (col - 64)] = f2bf(sig);
        } else {
          const float cc = tanhf(v);
          const size_t i64 = (size_t)row * 64 + col;
          const float u = bf2f(ubuf[i64]);
          const float hn = u * hbuf[i64] + (1.f - u) * cc;
          hbuf[i64] = hn;
          outA[(size_t)row * RS + col] = f2bf(hn);
        }
      }
    }
}

// ---------------- final projection ----------------

__global__ __launch_bounds__(256) void k_proj(const float* __restrict__ h,
                                              const float* __restrict__ Wp,
                                              const float* __restrict__ bp,
                                              float* __restrict__ out) {
  int lane = threadIdx.x & 63;
  int r = blockIdx.x * 4 + (threadIdx.x >> 6);
  float p = h[(size_t)r * 64 + lane] * Wp[lane];
  for (int off = 32; off; off >>= 1) p += __shfl_down(p, off, 64);
  if (lane == 0) {
    int n = r >> 6, b = r & 63;
    out[b * N + n] = p + bp[0];
  }
}

// ---------------- host launch ----------------

extern "C" void kernel_launch(void* const* d_in, const int* in_sizes, int n_in,
                              void* d_out, int out_size, void* d_ws, size_t ws_size,
                              hipStream_t stream) {
  const float* inp  = (const float*)d_in[0];
  const float* S    = (const float*)d_in[1];
  const float* eWru = (const float*)d_in[2];
  const float* ebru = (const float*)d_in[3];
  const float* eWc  = (const float*)d_in[4];
  const float* ebc  = (const float*)d_in[5];
  const float* dWru = (const float*)d_in[6];
  const float* dbru = (const float*)d_in[7];
  const float* dWc  = (const float*)d_in[8];
  const float* dbc  = (const float*)d_in[9];
  const float* Wp   = (const float*)d_in[10];
  const float* bp   = (const float*)d_in[11];
  float* out = (float*)d_out;

  char* p = (char*)d_ws;
  auto alloc = [&](size_t bytes) { void* q = p; p += (bytes + 255) & ~(size_t)255; return q; };
  u16*   A1    = (u16*)alloc((size_t)R * RS * 2);
  u16*   A2    = (u16*)alloc((size_t)R * RS * 2);
  float* hbuf  = (float*)alloc((size_t)R * 64 * 4);
  u16*   ubuf  = (u16*)alloc((size_t)R * 64 * 2);
  float* Xt    = (float*)alloc((size_t)T * R * 4);
  float* x1s   = (float*)alloc((size_t)T * R * 4);
  float* x2s   = (float*)alloc((size_t)T * R * 4);
  u16*   WtRUe = (u16*)alloc(128 * RS * 2);
  u16*   WtCe  = (u16*)alloc(64 * RS * 2);
  u16*   WtRUd = (u16*)alloc(128 * RS * 2);
  u16*   WtCd  = (u16*)alloc(64 * RS * 2);
  int*   rowptr = (int*)alloc(1024 * 4);
  int*   cols   = (int*)alloc(CSR_CAP * 4);
  float* vals   = (float*)alloc(CSR_CAP * 4);

  // init: zero A buffers (pads + initial h=0) and fp32 state
  hipMemsetAsync(A1, 0, (size_t)R * RS * 2, stream);
  hipMemsetAsync(A2, 0, (size_t)R * RS * 2, stream);
  hipMemsetAsync(hbuf, 0, (size_t)R * 64 * 4, stream);

  // prep: CSR, input transpose, scalar chains, transposed weights
  k_count<<<250, 256, 0, stream>>>(S, rowptr);
  k_scan<<<1, 1024, 0, stream>>>(rowptr);
  k_fill<<<250, 256, 0, stream>>>(S, rowptr, cols, vals);
  k_xt<<<dim3(16, T), 256, 0, stream>>>(inp, Xt);
  k_sspmv<<<dim3(N, T), 64, 0, stream>>>(rowptr, cols, vals, Xt, nullptr, x1s, 0);
  k_sspmv<<<dim3(N, T), 64, 0, stream>>>(rowptr, cols, vals, x1s, Xt, x2s, 1);
  k_wprep<<<dim3(112, 4), 256, 0, stream>>>(eWru, eWc, dWru, dWc,
                                            WtRUe, WtCe, WtRUd, WtCd);

  auto cell = [&](int t, const u16* Wru, const float* bru,
                  const u16* Wc, const float* bc) {
    const int xmode = (t >= 0) ? 1 : 2;
    const float* xs0 = (t >= 0) ? Xt  + (size_t)t * R : Xt;
    const float* xs1 = (t >= 0) ? x1s + (size_t)t * R : Xt;
    const float* xs2 = (t >= 0) ? x2s + (size_t)t * R : Xt;
    // gconv1 on A1 (seg0 = h)
    k_spmvb<<<N, 256, 0, stream>>>(rowptr, cols, vals, A1, nullptr, A1 + 64,
                                   xs0, xs1, xs2, A1, A2, xmode);
    k_spmvb<<<N, 256, 0, stream>>>(rowptr, cols, vals, A1 + 64, A1, A1 + 128,
                                   nullptr, nullptr, nullptr, nullptr, nullptr, 0);
    k_mgemm<0><<<500, 256, 0, stream>>>(A1, Wru, bru, A2, ubuf, hbuf);
    // gconv2 on A2 (seg0 = r.*h)
    k_spmvb<<<N, 256, 0, stream>>>(rowptr, cols, vals, A2, nullptr, A2 + 64,
                                   nullptr, nullptr, nullptr, nullptr, nullptr, 0);
    k_spmvb<<<N, 256, 0, stream>>>(rowptr, cols, vals, A2 + 64, A2, A2 + 128,
                                   nullptr, nullptr, nullptr, nullptr, nullptr, 0);
    k_mgemm<1><<<500, 256, 0, stream>>>(A2, Wc, bc, A1, ubuf, hbuf);
  };

  for (int t = 0; t < T; ++t) cell(t, WtRUe, ebru, WtCe, ebc);  // encoder
  cell(-1, WtRUd, dbru, WtCd, dbc);                             // decoder

  k_proj<<<16000, 256, 0, stream>>>(hbuf, Wp, bp, out);
  (void)in_sizes; (void)n_in; (void)out_size; (void)ws_size;
}

// Round 4
// 1118.586 us; speedup vs baseline: 5.0553x; 1.2565x over previous
//
#include <hip/hip_runtime.h>
#include <hip/hip_bf16.h>

namespace {
constexpr int B  = 64;
constexpr int T  = 8;
constexpr int N  = 1000;
constexpr int U  = 64;
constexpr int R  = B * N;        // 64000 rows (r = n*64 + b)
constexpr int RS = 256;          // padded K / row stride (512B rows, line-aligned)
constexpr int CSR_CAP = 65536;
}

typedef short bf16x8 __attribute__((ext_vector_type(8)));
typedef float f32x4  __attribute__((ext_vector_type(4)));
typedef unsigned short u16;

__device__ __forceinline__ float bf2f(u16 x) {
  unsigned u = ((unsigned)x) << 16;
  float f; __builtin_memcpy(&f, &u, 4); return f;
}
__device__ __forceinline__ u16 f2bf(float f) {
  unsigned u; __builtin_memcpy(&u, &f, 4);
  u += 0x7FFFu + ((u >> 16) & 1u);
  return (u16)(u >> 16);
}

// ---------------- CSR build (deterministic, no atomics) ----------------

__global__ __launch_bounds__(256) void k_count(const float* __restrict__ S,
                                               int* __restrict__ rowptr) {
  int lane = threadIdx.x & 63;
  int m = blockIdx.x * 4 + (threadIdx.x >> 6);
  int c = 0;
  for (int n = lane; n < N; n += 64) c += (S[m * N + n] != 0.f) ? 1 : 0;
  for (int off = 32; off; off >>= 1) c += __shfl_down(c, off, 64);
  if (lane == 0) rowptr[m + 1] = c;
}

__global__ __launch_bounds__(1024) void k_scan(int* __restrict__ rowptr) {
  __shared__ int sm[1024];
  int t = threadIdx.x;
  sm[t] = (t < N) ? rowptr[t + 1] : 0;
  __syncthreads();
  for (int off = 1; off < 1024; off <<= 1) {
    int v = sm[t];
    int a = (t >= off) ? sm[t - off] : 0;
    __syncthreads();
    sm[t] = v + a;
    __syncthreads();
  }
  if (t < N) rowptr[t + 1] = sm[t];
  if (t == 0) rowptr[0] = 0;
}

__global__ __launch_bounds__(256) void k_fill(const float* __restrict__ S,
                                              const int* __restrict__ rowptr,
                                              int* __restrict__ cols,
                                              float* __restrict__ vals) {
  int lane = threadIdx.x & 63;
  int m = blockIdx.x * 4 + (threadIdx.x >> 6);
  int base = rowptr[m];
  for (int n0 = 0; n0 < N; n0 += 64) {
    int n = n0 + lane;
    float v = (n < N) ? S[m * N + n] : 0.f;
    bool nz = (v != 0.f);
    unsigned long long mask = __ballot(nz);
    int pos = base + (int)__popcll(mask & ((1ull << lane) - 1ull));
    if (nz && pos < CSR_CAP) { cols[pos] = n; vals[pos] = v; }
    base += (int)__popcll(mask);
  }
}

// ---------------- inputs transpose: (B,T,N) -> Xt[t][n*64+b] fp32 ----------

__global__ __launch_bounds__(256) void k_xt(const float* __restrict__ inp,
                                            float* __restrict__ xT) {
  __shared__ float tile[64][65];
  const int t  = blockIdx.y;
  const int n0 = blockIdx.x * 64;
  const int lx = threadIdx.x & 63;
  const int ly = threadIdx.x >> 6;
  for (int bb = ly; bb < 64; bb += 4) {
    int n = n0 + lx;
    tile[bb][lx] = (n < N) ? inp[(bb * T + t) * N + n] : 0.f;
  }
  __syncthreads();
  for (int nn = ly; nn < 64; nn += 4) {
    int n = n0 + nn;
    if (n < N) xT[((size_t)t * N + n) * 64 + lx] = tile[lx][nn];
  }
}

// ---------------- scalar Chebyshev chain (fp32, all timesteps) -------------

__global__ __launch_bounds__(64) void k_sspmv(const int* __restrict__ rowptr,
                                              const int* __restrict__ cols,
                                              const float* __restrict__ vals,
                                              const float* __restrict__ in,
                                              const float* __restrict__ sub,
                                              float* __restrict__ out, int cheb) {
  const int m = blockIdx.x, b = threadIdx.x;
  const size_t toff = (size_t)blockIdx.y * R;
  float acc = 0.f;
  for (int j = rowptr[m]; j < rowptr[m + 1]; ++j)
    acc = fmaf(vals[j], in[toff + cols[j] * 64 + b], acc);
  if (cheb) acc = 2.f * acc - sub[toff + m * 64 + b];
  out[toff + m * 64 + b] = acc;
}

// ---------------- W transpose+reorder -> Wt[o][256] bf16 -------------------
// kp<192: original row ((kp&63)+1)*3 + (kp>>6);  192..194: row kp-192; else 0.

__global__ __launch_bounds__(256) void k_wprep(
    const float* __restrict__ w0, const float* __restrict__ w1,
    const float* __restrict__ w2, const float* __restrict__ w3,
    u16* __restrict__ o0, u16* __restrict__ o1,
    u16* __restrict__ o2, u16* __restrict__ o3) {
  const float* W; u16* O; int ncol;
  switch (blockIdx.y) {
    case 0:  W = w0; O = o0; ncol = 128; break;
    case 1:  W = w1; O = o1; ncol = 64;  break;
    case 2:  W = w2; O = o2; ncol = 128; break;
    default: W = w3; O = o3; ncol = 64;  break;
  }
  int idx = blockIdx.x * 256 + threadIdx.x;
  if (idx >= ncol * RS) return;
  int o = idx / RS, kp = idx - o * RS;
  float v = 0.f;
  if (kp < 192)      v = W[(((kp & 63) + 1) * 3 + (kp >> 6)) * ncol + o];
  else if (kp < 195) v = W[(kp - 192) * ncol + o];
  O[idx] = f2bf(v);
}

// ---------------- bf16 diffusion spmv, XCD-pinned batch chunks -------------
// grid (8, 125): blockIdx.x = chunk (8 batches) == XCD (x-major round-robin);
// blockIdx.y = group of 8 nodes. Thread (ml = tid>>5, l = tid&31) owns
// batch b = chunk*8 + (l>>2), 16 bf16 at col (l&3)*16 of node m.
// Per-XCD gather working set = 1000 nodes * 8 b * 128B = 1MB (fits 4MB L2).
// out = S@in (sub==null) or 2*S@in - sub. xmode: 1 write scalar slots from
// xs*, 2 write zeros, 0 none.

__global__ __launch_bounds__(256) void k_spmvb(
    const int* __restrict__ rowptr, const int* __restrict__ cols,
    const float* __restrict__ vals,
    const u16* __restrict__ in, const u16* __restrict__ sub,
    u16* __restrict__ out,
    const float* __restrict__ xs0, const float* __restrict__ xs1,
    const float* __restrict__ xs2,
    u16* __restrict__ scA, u16* __restrict__ scB, int xmode) {
  const int chunk = blockIdx.x;
  const int ml = threadIdx.x >> 5;
  const int l  = threadIdx.x & 31;
  const int m  = blockIdx.y * 8 + ml;
  const int b  = chunk * 8 + (l >> 2);
  const int col = (l & 3) * 16;
  const int s = rowptr[m], e = rowptr[m + 1];

  float acc[16];
#pragma unroll
  for (int i = 0; i < 16; ++i) acc[i] = 0.f;

  int j = s;
  for (; j + 1 < e; j += 2) {
    const float v0 = vals[j], v1 = vals[j + 1];
    const u16* p0 = in + ((size_t)cols[j]     * 64 + b) * RS + col;
    const u16* p1 = in + ((size_t)cols[j + 1] * 64 + b) * RS + col;
    bf16x8 a0 = *(const bf16x8*)p0, a1 = *(const bf16x8*)(p0 + 8);
    bf16x8 c0 = *(const bf16x8*)p1, c1 = *(const bf16x8*)(p1 + 8);
#pragma unroll
    for (int i = 0; i < 8; ++i) {
      acc[i]     = fmaf(v0, bf2f((u16)a0[i]), acc[i]);
      acc[i]     = fmaf(v1, bf2f((u16)c0[i]), acc[i]);
      acc[i + 8] = fmaf(v0, bf2f((u16)a1[i]), acc[i + 8]);
      acc[i + 8] = fmaf(v1, bf2f((u16)c1[i]), acc[i + 8]);
    }
  }
  if (j < e) {
    const float v = vals[j];
    const u16* p = in + ((size_t)cols[j] * 64 + b) * RS + col;
    bf16x8 q0 = *(const bf16x8*)p, q1 = *(const bf16x8*)(p + 8);
#pragma unroll
    for (int i = 0; i < 8; ++i) {
      acc[i]     = fmaf(v, bf2f((u16)q0[i]), acc[i]);
      acc[i + 8] = fmaf(v, bf2f((u16)q1[i]), acc[i + 8]);
    }
  }

  const size_t ro = ((size_t)m * 64 + b) * RS + col;
  if (sub) {
    bf16x8 s0 = *(const bf16x8*)(sub + ro);
    bf16x8 s1 = *(const bf16x8*)(sub + ro + 8);
#pragma unroll
    for (int i = 0; i < 8; ++i) acc[i]     = 2.f * acc[i]     - bf2f((u16)s0[i]);
#pragma unroll
    for (int i = 0; i < 8; ++i) acc[i + 8] = 2.f * acc[i + 8] - bf2f((u16)s1[i]);
  }
  bf16x8 o0, o1;
#pragma unroll
  for (int i = 0; i < 8; ++i) { o0[i] = (short)f2bf(acc[i]); o1[i] = (short)f2bf(acc[i + 8]); }
  *(bf16x8*)(out + ro) = o0;
  *(bf16x8*)(out + ro + 8) = o1;

  if (xmode && (l & 3) == 0) {
    const int r = m * 64 + b;
    u16 s0v = 0, s1v = 0, s2v = 0;
    if (xmode == 1) { s0v = f2bf(xs0[r]); s1v = f2bf(xs1[r]); s2v = f2bf(xs2[r]); }
    const size_t o = (size_t)r * RS + 192;
    scA[o] = s0v; scA[o + 1] = s1v; scA[o + 2] = s2v;
    scB[o] = s0v; scB[o + 1] = s1v; scB[o + 2] = s2v;
  }
}

// ---------------- MFMA GEMM: (64000 x 256) x (256 x NCOL) ------------------
// EPI=0 (NCOL=128, ru): sig = sigmoid(y+b); col<64 -> outA seg0 = bf16(sig*h)
//                       col>=64 -> ubuf = bf16(sig)
// EPI=1 (NCOL=64, c):   c = tanh(y+b); hn = u*h+(1-u)*c; hbuf=hn (fp32),
//                       outA seg0 = bf16(hn)

template <int EPI>
__global__ __launch_bounds__(256) void k_mgemm(
    const u16* __restrict__ A, const u16* __restrict__ Wt,
    const float* __restrict__ bias,
    u16* __restrict__ outA, u16* __restrict__ ubuf,
    float* __restrict__ hbuf) {
  constexpr int NF = EPI ? 4 : 8;
  const int l  = threadIdx.x & 63;
  const int wv = threadIdx.x >> 6;
  const int lr = l & 15, lk = l >> 4;
  const int r0 = blockIdx.x * 128 + wv * 32;

  f32x4 acc[2][NF];
#pragma unroll
  for (int i = 0; i < 2; ++i)
#pragma unroll
    for (int j = 0; j < NF; ++j) acc[i][j] = (f32x4){0.f, 0.f, 0.f, 0.f};

  const u16* pa0 = A + (size_t)(r0 + lr) * RS + lk * 8;
  const u16* pa1 = pa0 + 16 * RS;
  const u16* pw  = Wt + (size_t)lr * RS + lk * 8;

#pragma unroll
  for (int ks = 0; ks < 8; ++ks) {
    bf16x8 a0 = *(const bf16x8*)(pa0 + ks * 32);
    bf16x8 a1 = *(const bf16x8*)(pa1 + ks * 32);
#pragma unroll
    for (int cb = 0; cb < NF; ++cb) {
      bf16x8 bb = *(const bf16x8*)(pw + (size_t)cb * (16 * RS) + ks * 32);
      acc[0][cb] = __builtin_amdgcn_mfma_f32_16x16x32_bf16(a0, bb, acc[0][cb], 0, 0, 0);
      acc[1][cb] = __builtin_amdgcn_mfma_f32_16x16x32_bf16(a1, bb, acc[1][cb], 0, 0, 0);
    }
  }

#pragma unroll
  for (int mf = 0; mf < 2; ++mf)
#pragma unroll
    for (int cb = 0; cb < NF; ++cb) {
      const int col = cb * 16 + lr;
      const float bs = bias[col];
#pragma unroll
      for (int j = 0; j < 4; ++j) {
        const int row = r0 + mf * 16 + lk * 4 + j;
        const float v = acc[mf][cb][j] + bs;
        if (EPI == 0) {
          const float sig = 1.f / (1.f + expf(-v));
          if (col < 64)
            outA[(size_t)row * RS + col] = f2bf(sig * hbuf[(size_t)row * 64 + col]);
          else
            ubuf[(size_t)row * 64 + (col - 64)] = f2bf(sig);
        } else {
          const float cc = tanhf(v);
          const size_t i64 = (size_t)row * 64 + col;
          const float u = bf2f(ubuf[i64]);
          const float hn = u * hbuf[i64] + (1.f - u) * cc;
          hbuf[i64] = hn;
          outA[(size_t)row * RS + col] = f2bf(hn);
        }
      }
    }
}

// ---------------- final projection ----------------

__global__ __launch_bounds__(256) void k_proj(const float* __restrict__ h,
                                              const float* __restrict__ Wp,
                                              const float* __restrict__ bp,
                                              float* __restrict__ out) {
  int lane = threadIdx.x & 63;
  int r = blockIdx.x * 4 + (threadIdx.x >> 6);
  float p = h[(size_t)r * 64 + lane] * Wp[lane];
  for (int off = 32; off; off >>= 1) p += __shfl_down(p, off, 64);
  if (lane == 0) {
    int n = r >> 6, b = r & 63;
    out[b * N + n] = p + bp[0];
  }
}

// ---------------- host launch ----------------

extern "C" void kernel_launch(void* const* d_in, const int* in_sizes, int n_in,
                              void* d_out, int out_size, void* d_ws, size_t ws_size,
                              hipStream_t stream) {
  const float* inp  = (const float*)d_in[0];
  const float* S    = (const float*)d_in[1];
  const float* eWru = (const float*)d_in[2];
  const float* ebru = (const float*)d_in[3];
  const float* eWc  = (const float*)d_in[4];
  const float* ebc  = (const float*)d_in[5];
  const float* dWru = (const float*)d_in[6];
  const float* dbru = (const float*)d_in[7];
  const float* dWc  = (const float*)d_in[8];
  const float* dbc  = (const float*)d_in[9];
  const float* Wp   = (const float*)d_in[10];
  const float* bp   = (const float*)d_in[11];
  float* out = (float*)d_out;

  char* p = (char*)d_ws;
  auto alloc = [&](size_t bytes) { void* q = p; p += (bytes + 255) & ~(size_t)255; return q; };
  u16*   A1    = (u16*)alloc((size_t)R * RS * 2);
  u16*   A2    = (u16*)alloc((size_t)R * RS * 2);
  float* hbuf  = (float*)alloc((size_t)R * 64 * 4);
  u16*   ubuf  = (u16*)alloc((size_t)R * 64 * 2);
  float* Xt    = (float*)alloc((size_t)T * R * 4);
  float* x1s   = (float*)alloc((size_t)T * R * 4);
  float* x2s   = (float*)alloc((size_t)T * R * 4);
  u16*   WtRUe = (u16*)alloc(128 * RS * 2);
  u16*   WtCe  = (u16*)alloc(64 * RS * 2);
  u16*   WtRUd = (u16*)alloc(128 * RS * 2);
  u16*   WtCd  = (u16*)alloc(64 * RS * 2);
  int*   rowptr = (int*)alloc(1024 * 4);
  int*   cols   = (int*)alloc(CSR_CAP * 4);
  float* vals   = (float*)alloc(CSR_CAP * 4);

  // A1 seg0 must start as h=0 (pads are never read against nonzero W rows;
  // A2 needs no clear: its seg0/scalars are fully written before any read).
  hipMemsetAsync(A1, 0, (size_t)R * RS * 2, stream);
  hipMemsetAsync(hbuf, 0, (size_t)R * 64 * 4, stream);

  // prep: CSR, input transpose, scalar chains, transposed weights
  k_count<<<250, 256, 0, stream>>>(S, rowptr);
  k_scan<<<1, 1024, 0, stream>>>(rowptr);
  k_fill<<<250, 256, 0, stream>>>(S, rowptr, cols, vals);
  k_xt<<<dim3(16, T), 256, 0, stream>>>(inp, Xt);
  k_sspmv<<<dim3(N, T), 64, 0, stream>>>(rowptr, cols, vals, Xt, nullptr, x1s, 0);
  k_sspmv<<<dim3(N, T), 64, 0, stream>>>(rowptr, cols, vals, x1s, Xt, x2s, 1);
  k_wprep<<<dim3(128, 4), 256, 0, stream>>>(eWru, eWc, dWru, dWc,
                                            WtRUe, WtCe, WtRUd, WtCd);

  dim3 gs(8, 125);

  auto cell = [&](int t, const u16* Wru, const float* bru,
                  const u16* Wc, const float* bc) {
    const int xmode = (t >= 0) ? 1 : 2;
    const float* xs0 = (t >= 0) ? Xt  + (size_t)t * R : Xt;
    const float* xs1 = (t >= 0) ? x1s + (size_t)t * R : Xt;
    const float* xs2 = (t >= 0) ? x2s + (size_t)t * R : Xt;
    // gconv1 on A1 (seg0 = h)
    k_spmvb<<<gs, 256, 0, stream>>>(rowptr, cols, vals, A1, nullptr, A1 + 64,
                                    xs0, xs1, xs2, A1, A2, xmode);
    k_spmvb<<<gs, 256, 0, stream>>>(rowptr, cols, vals, A1 + 64, A1, A1 + 128,
                                    nullptr, nullptr, nullptr, nullptr, nullptr, 0);
    k_mgemm<0><<<500, 256, 0, stream>>>(A1, Wru, bru, A2, ubuf, hbuf);
    // gconv2 on A2 (seg0 = r.*h)
    k_spmvb<<<gs, 256, 0, stream>>>(rowptr, cols, vals, A2, nullptr, A2 + 64,
                                    nullptr, nullptr, nullptr, nullptr, nullptr, 0);
    k_spmvb<<<gs, 256, 0, stream>>>(rowptr, cols, vals, A2 + 64, A2, A2 + 128,
                                    nullptr, nullptr, nullptr, nullptr, nullptr, 0);
    k_mgemm<1><<<500, 256, 0, stream>>>(A2, Wc, bc, A1, ubuf, hbuf);
  };

  for (int t = 0; t < T; ++t) cell(t, WtRUe, ebru, WtCe, ebc);  // encoder
  cell(-1, WtRUd, dbru, WtCd, dbc);                             // decoder

  k_proj<<<16000, 256, 0, stream>>>(hbuf, Wp, bp, out);
  (void)in_sizes; (void)n_in; (void)out_size; (void)ws_size;
}